// Round 6
// baseline (498.264 us; speedup 1.0000x reference)
//
#include <hip/hip_runtime.h>
#include <cfloat>
#include <cmath>

#define B_   8
#define N_   8192
#define S_   2048
#define C1_  128
#define C2_  256
#define T_   256
#define CIN_ 384
#define CO_  256

#define KCH  8           // knn S-chunks
#define KCS  (S_ / KCH)  // 256 candidates per chunk
#define KQB  512         // queries per knn block (256 thr x 2 queries)

typedef __attribute__((ext_vector_type(8))) short short8;
typedef __attribute__((ext_vector_type(4))) float f32x4;

// ---------- helpers ----------
__device__ __forceinline__ float bf2f(unsigned short u) {
    union { unsigned int i; float f; } v; v.i = ((unsigned int)u) << 16; return v.f;
}
__device__ __forceinline__ unsigned short f2bf(float f) {
    union { float f; unsigned int i; } v; v.f = f;
    unsigned int i = v.i;
    unsigned int r = i + 0x7FFFu + ((i >> 16) & 1u);   // RNE
    return (unsigned short)(r >> 16);
}
__device__ __forceinline__ float gelu_f(float x) {
    return 0.5f * x * (1.0f + erff(x * 0.70710678118654752440f));
}
__device__ __forceinline__ void async16(const void* g, void* l) {
    __builtin_amdgcn_global_load_lds((const __attribute__((address_space(1))) void*)g,
                                     (__attribute__((address_space(3))) void*)l, 16, 0, 0);
}
__device__ __forceinline__ float med3f(float a, float b, float c) {
    float r;
    asm("v_med3_f32 %0, %1, %2, %3" : "=v"(r) : "v"(a), "v"(b), "v"(c));
    return r;
}

// ---------- ws layout (bytes) ----------
#define OFF_TE1   0u          // 8*384*4 = 12288
#define OFF_TE2   16384u      // 8*256*4 = 8192
#define OFF_ST    32768u      // psum1(1024) psq1(1024) psum2(1024) psq2(1024)
#define OFF_WC1   1605632u    // 98304*2
#define OFF_WC2   1802240u    // 65536*2
#define OFF_P2T   2097152u    // 8*2048*256*2 = 8388608 (bf16)
#define OFF_X1    10485760u   // 8*8192*384*2 = 50331648 (bf16; Z reuses)
#define OFF_Y     60817408u   // 8*8192*256*2 = 33554432 (bf16)
// transient tenants:
#define OFF_PD    OFF_Y                     // knn dist partials (dead before gemm1 writes Y)
#define OFF_PI    (OFF_Y + 6291456u)        // 8*8*8192*3*4 = 6.29 MB each

// ===================================================================
// mega1: knn partials (blocks 0..1023) + prep (1024..1415)
//        + transpose_p2 (1416..5511) + stat-zero (5512)
// ===================================================================
__global__ __launch_bounds__(256) void mega1_kernel(
    const float* __restrict__ xyz1, const float* __restrict__ xyz2,
    float* __restrict__ pd, int* __restrict__ pi,
    const float* __restrict__ w1, const float* __restrict__ w2,
    unsigned short* __restrict__ o1, unsigned short* __restrict__ o2,
    const float* __restrict__ t_embed,
    const float* __restrict__ w_t1, const float* __restrict__ b_t1,
    const float* __restrict__ w_t2, const float* __restrict__ b_t2,
    float* __restrict__ te1, float* __restrict__ te2,
    const float* __restrict__ p2, unsigned short* __restrict__ p2t,
    float* __restrict__ stats)
{
    __shared__ __align__(16) char smem[4096];
    int bx = blockIdx.x, tid = threadIdx.x;

    if (bx < 1024) {
        // ---- knn partials ----
        float4* sp = (float4*)smem;
        int x = bx & 15, ch = (bx >> 4) & 7, b = bx >> 7;
        int s0 = ch * KCS;
        {
            int gs = s0 + tid;
            float xx = xyz2[(b * S_ + gs) * 3 + 0];
            float yy = xyz2[(b * S_ + gs) * 3 + 1];
            float zz = xyz2[(b * S_ + gs) * 3 + 2];
            sp[tid] = make_float4(xx, yy, zz, xx * xx + yy * yy + zz * zz);
        }
        __syncthreads();

        float nx[2], ny[2], nz[2], nn[2];
        float d1[2], d2[2], d3[2];
        int   i1[2], i2[2], i3[2];
        #pragma unroll
        for (int qq = 0; qq < 2; ++qq) {
            int n = x * KQB + qq * 256 + tid;
            float x1 = xyz1[(b * N_ + n) * 3 + 0];
            float y1 = xyz1[(b * N_ + n) * 3 + 1];
            float z1 = xyz1[(b * N_ + n) * 3 + 2];
            nn[qq] = x1 * x1 + y1 * y1 + z1 * z1;
            nx[qq] = -2.0f * x1; ny[qq] = -2.0f * y1; nz[qq] = -2.0f * z1;
            d1[qq] = FLT_MAX; d2[qq] = FLT_MAX; d3[qq] = FLT_MAX;
            i1[qq] = 0; i2[qq] = 0; i3[qq] = 0;
        }

        for (int s = 0; s < KCS; s += 4) {
            #pragma unroll
            for (int u = 0; u < 4; ++u) {
                float4 p = sp[s + u];
                int gi = s0 + s + u;
                #pragma unroll
                for (int qq = 0; qq < 2; ++qq) {
                    float d = fmaf(nx[qq], p.x,
                              fmaf(ny[qq], p.y,
                              fmaf(nz[qq], p.z, p.w)));
                    bool c1 = d < d1[qq];
                    bool c2 = d < d2[qq];
                    bool c3 = d < d3[qq];
                    float e1 = fminf(d1[qq], d);
                    float e2 = med3f(d1[qq], d2[qq], d);
                    float e3 = med3f(d2[qq], d3[qq], d);
                    int u1  = c1 ? i1[qq] : gi;
                    int n1i = c1 ? gi : i1[qq];
                    int n2i = c2 ? u1 : i2[qq];
                    int u2  = c2 ? i2[qq] : gi;
                    int n3i = c3 ? u2 : i3[qq];
                    d1[qq] = e1; d2[qq] = e2; d3[qq] = e3;
                    i1[qq] = n1i; i2[qq] = n2i; i3[qq] = n3i;
                }
            }
        }

        #pragma unroll
        for (int qq = 0; qq < 2; ++qq) {
            int n = x * KQB + qq * 256 + tid;
            size_t pb = (((size_t)b * KCH + ch) * N_ + n) * 3;
            pd[pb + 0] = d1[qq] + nn[qq];
            pd[pb + 1] = d2[qq] + nn[qq];
            pd[pb + 2] = d3[qq] + nn[qq];
            pi[pb + 0] = i1[qq]; pi[pb + 1] = i2[qq]; pi[pb + 2] = i3[qq];
        }
    } else if (bx < 1416) {
        // ---- prep: weight cvt + te1/te2 ----
        int pbx = bx - 1024;
        if (pbx < 384) {
            int g = pbx * 256 + tid;
            o1[g] = f2bf(w1[g]);
            if (g < CO_ * CO_) o2[g] = f2bf(w2[g]);
            return;
        }
        float* gt = (float*)smem;
        int b = pbx - 384;
        gt[tid] = gelu_f(t_embed[b * T_ + tid]);
        __syncthreads();
        for (int o = tid; o < CIN_ + CO_; o += 256) {
            if (o < CIN_) {
                const float* w = w_t1 + o * T_;
                float s = 0.f;
                for (int k = 0; k < T_; ++k) s += gt[k] * w[k];
                te1[b * CIN_ + o] = s + b_t1[o];
            } else {
                int oo = o - CIN_;
                const float* w = w_t2 + oo * T_;
                float s = 0.f;
                for (int k = 0; k < T_; ++k) s += gt[k] * w[k];
                te2[b * CO_ + oo] = s + b_t2[oo];
            }
        }
    } else if (bx < 5512) {
        // ---- transpose p2 (B,C2,S) fp32 -> (B,S,C2) bf16 ----
        unsigned short (*tile)[33] = (unsigned short (*)[33])smem;
        int bz = bx - 1416;
        int b = bz >> 9, cy = (bz >> 6) & 7, sx = bz & 63;
        int s0 = sx * 32, c0 = cy * 32;
        int tx = tid & 31, ty = tid >> 5;
        #pragma unroll
        for (int j = 0; j < 4; ++j) {
            int c = ty + j * 8;
            tile[c][tx] = f2bf(p2[((size_t)b * C2_ + c0 + c) * S_ + s0 + tx]);
        }
        __syncthreads();
        #pragma unroll
        for (int j = 0; j < 4; ++j) {
            int s = ty + j * 8;
            p2t[((size_t)b * S_ + s0 + s) * C2_ + c0 + tx] = tile[tx][s];
        }
    } else {
        // ---- zero BN-stat accumulators (4 x 256 floats) ----
        stats[tid] = 0.f; stats[tid + 256] = 0.f;
        stats[tid + 512] = 0.f; stats[tid + 768] = 0.f;
    }
}

// ===================================================================
// mega2: interp (blocks 0..8191) + transpose_p1 (8192..16383)
// ===================================================================
__global__ __launch_bounds__(256) void mega2_kernel(
    const float* __restrict__ pd, const int* __restrict__ pi,
    const unsigned short* __restrict__ p2t,
    const float* __restrict__ te1,
    const float* __restrict__ p1,
    unsigned short* __restrict__ X1)
{
    __shared__ __align__(16) char smem[4096];
    int bx = blockIdx.x, tid = threadIdx.x;

    if (bx < 8192) {
        // ---- merge partials + interp -> X1[:,128:384] ----
        float (*spd)[8][3] = (float (*)[8][3])smem;              // 8*8*3*4 = 768
        int   (*spi)[8][3] = (int (*)[8][3])(smem + 768);        // 768
        float* ste = (float*)(smem + 1536);                      // 1024
        int b = bx >> 10;
        int n0 = (bx & 1023) * 8;
        ste[tid] = te1[b * CIN_ + C1_ + tid];
        if (tid < 64) {
            int ch = tid >> 3, r = tid & 7;
            size_t pb = (((size_t)b * KCH + ch) * N_ + n0 + r) * 3;
            spd[ch][r][0] = pd[pb]; spd[ch][r][1] = pd[pb + 1]; spd[ch][r][2] = pd[pb + 2];
        } else if (tid < 128) {
            int t2 = tid - 64;
            int ch = t2 >> 3, r = t2 & 7;
            size_t pb = (((size_t)b * KCH + ch) * N_ + n0 + r) * 3;
            spi[ch][r][0] = pi[pb]; spi[ch][r][1] = pi[pb + 1]; spi[ch][r][2] = pi[pb + 2];
        }
        __syncthreads();

        int r = tid >> 5;
        int l = tid & 31;
        float d1, d2, d3; int i1, i2, i3;
        if (l < KCH) {
            d1 = spd[l][r][0]; d2 = spd[l][r][1]; d3 = spd[l][r][2];
            i1 = spi[l][r][0]; i2 = spi[l][r][1]; i3 = spi[l][r][2];
        } else {
            d1 = d2 = d3 = FLT_MAX;
            i1 = i2 = i3 = 0x7FFFFFFF;
        }
        #pragma unroll
        for (int m = 1; m <= 4; m <<= 1) {
            float pd1 = __shfl_xor(d1, m), pd2 = __shfl_xor(d2, m), pd3 = __shfl_xor(d3, m);
            int   pi1 = __shfl_xor(i1, m), pi2 = __shfl_xor(i2, m), pi3 = __shfl_xor(i3, m);
            #pragma unroll
            for (int k = 0; k < 3; ++k) {
                float d = (k == 0) ? pd1 : (k == 1) ? pd2 : pd3;
                int   i = (k == 0) ? pi1 : (k == 1) ? pi2 : pi3;
                bool c1 = (d < d1) || (d == d1 && i < i1);
                bool c2 = (d < d2) || (d == d2 && i < i2);
                bool c3 = (d < d3) || (d == d3 && i < i3);
                float e1 = c1 ? d : d1;        int j1 = c1 ? i : i1;
                float e2 = c1 ? d1 : (c2 ? d : d2);
                int   j2 = c1 ? i1 : (c2 ? i : i2);
                float e3 = c2 ? d2 : (c3 ? d : d3);
                int   j3 = c2 ? i2 : (c3 ? i : i3);
                d1 = e1; d2 = e2; d3 = e3; i1 = j1; i2 = j2; i3 = j3;
            }
        }
        int base = tid & 32;
        d1 = __shfl(d1, base); d2 = __shfl(d2, base); d3 = __shfl(d3, base);
        i1 = __shfl(i1, base); i2 = __shfl(i2, base); i3 = __shfl(i3, base);
        float r1 = 1.0f / (d1 + 1e-8f);
        float r2 = 1.0f / (d2 + 1e-8f);
        float r3 = 1.0f / (d3 + 1e-8f);
        float rs = 1.0f / (r1 + r2 + r3);
        float w0 = r1 * rs, w1 = r2 * rs, w2 = r3 * rs;

        int gr = (b << 13) + n0 + r;
        int co = l * 8;
        const unsigned short* q0 = p2t + ((size_t)b * S_ + i1) * C2_ + co;
        const unsigned short* q1 = p2t + ((size_t)b * S_ + i2) * C2_ + co;
        const unsigned short* q2 = p2t + ((size_t)b * S_ + i3) * C2_ + co;
        union { short8 v; unsigned short u[8]; } a0, a1, a2, pk;
        a0.v = *(const short8*)q0;
        a1.v = *(const short8*)q1;
        a2.v = *(const short8*)q2;
        #pragma unroll
        for (int jj = 0; jj < 8; ++jj) {
            float v = w0 * bf2f(a0.u[jj]) + w1 * bf2f(a1.u[jj]) + w2 * bf2f(a2.u[jj])
                    + ste[co + jj];
            pk.u[jj] = f2bf(v);
        }
        *(short8*)&X1[(size_t)gr * CIN_ + C1_ + co] = pk.v;
    } else {
        // ---- transpose p1 (B,128,N) fp32 + te1 -> X1[:,0:128] bf16 ----
        unsigned short (*tile)[33] = (unsigned short (*)[33])smem;
        int bz = bx - 8192;
        int b = bz >> 10, cy = (bz >> 8) & 3, nx = bz & 255;
        int n0 = nx * 32, c0 = cy * 32;
        int tx = tid & 31, ty = tid >> 5;
        const float* te = te1 + b * CIN_;
        #pragma unroll
        for (int j = 0; j < 4; ++j) {
            int c = ty + j * 8;
            tile[c][tx] =
                f2bf(p1[((size_t)b * C1_ + c0 + c) * N_ + n0 + tx] + te[c0 + c]);
        }
        __syncthreads();
        #pragma unroll
        for (int j = 0; j < 4; ++j) {
            int n = ty + j * 8;
            X1[((size_t)b * N_ + n0 + n) * CIN_ + c0 + tx] = tile[tx][n];
        }
    }
}

// ---------- GEMM (m97-style, B^T input) + atomic BN-stat accumulation ----------
template <int K, int MODE>
__global__ __launch_bounds__(256) void gemm_bt(
    const unsigned short* __restrict__ A,
    const unsigned short* __restrict__ X,
    const float* __restrict__ bias,
    unsigned short* __restrict__ out,
    float* __restrict__ psum, float* __restrict__ psq)
{
    __shared__ unsigned short sA[128 * 64];
    __shared__ unsigned short sB[128 * 64];
    const int tid = threadIdx.x;
    const int lane = tid & 63, wave = tid >> 6;
    const int wo = wave >> 1, wm = wave & 1;
    const int quad = lane >> 4, col = lane & 15;
    const int b = blockIdx.z;
    const int x = blockIdx.x;
    const int perm = (x & 7) * 16 + (x >> 3);
    const int n_t = perm >> 1, o_t = perm & 1;
    const int o0 = o_t * 128;
    const int n0 = n_t * 128;
    const unsigned short* Xb = X + (size_t)b * N_ * K;

    f32x4 acc[4][4];
    #pragma unroll
    for (int i = 0; i < 4; ++i)
        #pragma unroll
        for (int j = 0; j < 4; ++j) acc[i][j] = (f32x4){0.f, 0.f, 0.f, 0.f};

    for (int k0 = 0; k0 < K; k0 += 64) {
        #pragma unroll
        for (int i = 0; i < 4; ++i) {
            int chunk = i * 256 + tid;
            int row = chunk >> 3, c8 = chunk & 7;
            async16(&A [(o0 + row) * K + k0 + c8 * 8], &sA[chunk * 8]);
            async16(&Xb[(size_t)(n0 + row) * K + k0 + c8 * 8], &sB[chunk * 8]);
        }
        __syncthreads();
        #pragma unroll
        for (int kk = 0; kk < 64; kk += 32) {
            short8 af[4], bfr[4];
            #pragma unroll
            for (int i = 0; i < 4; ++i)
                af[i] = *(const short8*)&sA[(wo * 64 + i * 16 + col) * 64 + kk + quad * 8];
            #pragma unroll
            for (int j = 0; j < 4; ++j)
                bfr[j] = *(const short8*)&sB[(wm * 64 + j * 16 + col) * 64 + kk + quad * 8];
            #pragma unroll
            for (int i = 0; i < 4; ++i)
                #pragma unroll
                for (int j = 0; j < 4; ++j)
                    acc[i][j] = __builtin_amdgcn_mfma_f32_16x16x32_bf16(af[i], bfr[j], acc[i][j], 0, 0, 0);
        }
        __syncthreads();
    }

    #pragma unroll
    for (int i = 0; i < 4; ++i) {
        int oo = o0 + wo * 64 + i * 16 + quad * 4;
        float bv0 = bias[oo + 0], bv1 = bias[oo + 1];
        float bv2 = bias[oo + 2], bv3 = bias[oo + 3];
        float s0 = 0.f, s1 = 0.f, s2 = 0.f, s3 = 0.f;
        float q0 = 0.f, q1 = 0.f, q2 = 0.f, q3 = 0.f;
        #pragma unroll
        for (int j = 0; j < 4; ++j) {
            int nn = n0 + wm * 64 + j * 16 + col;
            float v0 = acc[i][j][0] + bv0, v1 = acc[i][j][1] + bv1;
            float v2 = acc[i][j][2] + bv2, v3 = acc[i][j][3] + bv3;
            s0 += v0; q0 += v0 * v0; s1 += v1; q1 += v1 * v1;
            s2 += v2; q2 += v2 * v2; s3 += v3; q3 += v3 * v3;
            if (MODE == 0) {
                union { unsigned short u[4]; uint2 p; } pk;
                pk.u[0] = f2bf(v0); pk.u[1] = f2bf(v1);
                pk.u[2] = f2bf(v2); pk.u[3] = f2bf(v3);
                *(uint2*)&out[((size_t)b * N_ + nn) * CO_ + oo] = pk.p;
            } else {
                out[((size_t)b * CO_ + oo + 0) * N_ + nn] = f2bf(v0);
                out[((size_t)b * CO_ + oo + 1) * N_ + nn] = f2bf(v1);
                out[((size_t)b * CO_ + oo + 2) * N_ + nn] = f2bf(v2);
                out[((size_t)b * CO_ + oo + 3) * N_ + nn] = f2bf(v3);
            }
        }
        #pragma unroll
        for (int off = 1; off < 16; off <<= 1) {
            s0 += __shfl_down(s0, off); q0 += __shfl_down(q0, off);
            s1 += __shfl_down(s1, off); q1 += __shfl_down(q1, off);
            s2 += __shfl_down(s2, off); q2 += __shfl_down(q2, off);
            s3 += __shfl_down(s3, off); q3 += __shfl_down(q3, off);
        }
        if (col == 0) {
            atomicAdd(&psum[oo + 0], s0); atomicAdd(&psum[oo + 1], s1);
            atomicAdd(&psum[oo + 2], s2); atomicAdd(&psum[oo + 3], s3);
            atomicAdd(&psq[oo + 0], q0); atomicAdd(&psq[oo + 1], q1);
            atomicAdd(&psq[oo + 2], q2); atomicAdd(&psq[oo + 3], q3);
        }
    }
}

// ---------- in-place: x2 = gelu(scale*y + shift) + te2; BN computed in-block ----------
__global__ __launch_bounds__(256) void apply1_kernel(
    unsigned short* __restrict__ y,
    const float* __restrict__ psum, const float* __restrict__ psq,
    const float* __restrict__ gamma, const float* __restrict__ beta,
    const float* __restrict__ te2)
{
    __shared__ float ssc[CO_], ssh[CO_], ste[CO_];
    int b = blockIdx.x >> 10;
    int t = threadIdx.x;
    {
        const float inv = 1.0f / 65536.0f;
        float s = psum[t], q = psq[t];
        float m = s * inv;
        float var = fmaxf(q * inv - m * m, 0.f);
        float sc = gamma[t] / sqrtf(var + 1e-5f);
        ssc[t] = sc;
        ssh[t] = beta[t] - m * sc;
        ste[t] = te2[b * CO_ + t];
    }
    __syncthreads();
    int g = blockIdx.x * 256 + t;
    int row = g >> 5;
    int og = (g & 31) * 8;
    unsigned short* p = y + (size_t)row * CO_ + og;
    union { short8 v; unsigned short u[8]; } in, op;
    in.v = *(short8*)p;
    #pragma unroll
    for (int jj = 0; jj < 8; ++jj) {
        int o = og + jj;
        op.u[jj] = f2bf(gelu_f(ssc[o] * bf2f(in.u[jj]) + ssh[o]) + ste[o]);
    }
    *(short8*)p = op.v;
}

// ---------- final: out = gelu(scale*z + shift); BN computed per-thread ----------
__global__ __launch_bounds__(256) void final_kernel(
    const unsigned short* __restrict__ z,
    const float* __restrict__ psum, const float* __restrict__ psq,
    const float* __restrict__ gamma, const float* __restrict__ beta,
    float* __restrict__ out)
{
    int bx = blockIdx.x;
    int o = (bx >> 2) & (CO_ - 1);      // one output channel per block
    const float inv = 1.0f / 65536.0f;
    float s = psum[o], q = psq[o];
    float m = s * inv;
    float var = fmaxf(q * inv - m * m, 0.f);
    float sc = gamma[o] / sqrtf(var + 1e-5f);
    float sh = beta[o] - m * sc;

    int g = bx * 256 + threadIdx.x;
    size_t e = (size_t)g * 8;
    union { short8 v; unsigned short u[8]; } in;
    in.v = *(const short8*)&z[e];
    float vo[8];
    #pragma unroll
    for (int jj = 0; jj < 8; ++jj)
        vo[jj] = gelu_f(sc * bf2f(in.u[jj]) + sh);
    *(float4*)&out[e]     = make_float4(vo[0], vo[1], vo[2], vo[3]);
    *(float4*)&out[e + 4] = make_float4(vo[4], vo[5], vo[6], vo[7]);
}

// ---------- launch ----------
extern "C" void kernel_launch(void* const* d_in, const int* in_sizes, int n_in,
                              void* d_out, int out_size, void* d_ws, size_t ws_size,
                              hipStream_t stream)
{
    (void)in_sizes; (void)n_in; (void)out_size; (void)ws_size;
    const float* xyz1    = (const float*)d_in[0];
    const float* xyz2    = (const float*)d_in[1];
    const float* points1 = (const float*)d_in[2];
    const float* points2 = (const float*)d_in[3];
    const float* t_embed = (const float*)d_in[4];
    const float* w_t1    = (const float*)d_in[5];
    const float* b_t1    = (const float*)d_in[6];
    const float* w_c1    = (const float*)d_in[7];
    const float* b_c1    = (const float*)d_in[8];
    const float* g1      = (const float*)d_in[9];
    const float* be1     = (const float*)d_in[10];
    const float* w_t2    = (const float*)d_in[11];
    const float* b_t2    = (const float*)d_in[12];
    const float* w_c2    = (const float*)d_in[13];
    const float* b_c2    = (const float*)d_in[14];
    const float* g2      = (const float*)d_in[15];
    const float* be2     = (const float*)d_in[16];

    char* w = (char*)d_ws;
    float* te1        = (float*)(w + OFF_TE1);
    float* te2        = (float*)(w + OFF_TE2);
    float* stats      = (float*)(w + OFF_ST);
    float* psum1      = stats;
    float* psq1       = stats + 256;
    float* psum2      = stats + 512;
    float* psq2       = stats + 768;
    unsigned short* wc1 = (unsigned short*)(w + OFF_WC1);
    unsigned short* wc2 = (unsigned short*)(w + OFF_WC2);
    unsigned short* p2t = (unsigned short*)(w + OFF_P2T);
    float* pd         = (float*)(w + OFF_PD);
    int*   pi         = (int*)(w + OFF_PI);
    unsigned short* X1  = (unsigned short*)(w + OFF_X1);
    unsigned short* Z   = (unsigned short*)(w + OFF_X1);
    unsigned short* Y   = (unsigned short*)(w + OFF_Y);
    float* out = (float*)d_out;

    hipLaunchKernelGGL(mega1_kernel, dim3(5513), dim3(256), 0, stream,
                       xyz1, xyz2, pd, pi,
                       w_c1, w_c2, wc1, wc2,
                       t_embed, w_t1, b_t1, w_t2, b_t2, te1, te2,
                       points2, p2t, stats);
    hipLaunchKernelGGL(mega2_kernel, dim3(16384), dim3(256), 0, stream,
                       pd, pi, p2t, te1, points1, X1);
    // gemm1 writes Y, overwriting pd/pi (dead after mega2)
    hipLaunchKernelGGL((gemm_bt<CIN_, 0>), dim3(128, 1, B_), dim3(256), 0, stream,
                       wc1, X1, b_c1, Y, psum1, psq1);
    hipLaunchKernelGGL(apply1_kernel, dim3(8192), dim3(256), 0, stream,
                       Y, psum1, psq1, g1, be1, te2);
    hipLaunchKernelGGL((gemm_bt<CO_, 1>), dim3(128, 1, B_), dim3(256), 0, stream,
                       wc2, Y, b_c2, Z, psum2, psq2);
    hipLaunchKernelGGL(final_kernel, dim3(8192), dim3(256), 0, stream,
                       Z, psum2, psq2, g2, be2, out);
}

// Round 8
// 319.039 us; speedup vs baseline: 1.5618x; 1.5618x over previous
//
#include <hip/hip_runtime.h>
#include <cfloat>
#include <cmath>

#define B_   8
#define N_   8192
#define S_   2048
#define C1_  128
#define C2_  256
#define T_   256
#define CIN_ 384
#define CO_  256

#define KCH  8           // knn S-chunks
#define KCS  (S_ / KCH)  // 256 candidates per chunk
#define KQB  512         // queries per knn block (256 thr x 2 queries)

typedef __attribute__((ext_vector_type(8))) short short8;
typedef __attribute__((ext_vector_type(4))) float f32x4;

// ---------- helpers ----------
__device__ __forceinline__ float bf2f(unsigned short u) {
    union { unsigned int i; float f; } v; v.i = ((unsigned int)u) << 16; return v.f;
}
__device__ __forceinline__ unsigned short f2bf(float f) {
    union { float f; unsigned int i; } v; v.f = f;
    unsigned int i = v.i;
    unsigned int r = i + 0x7FFFu + ((i >> 16) & 1u);   // RNE
    return (unsigned short)(r >> 16);
}
__device__ __forceinline__ float gelu_f(float x) {
    return 0.5f * x * (1.0f + erff(x * 0.70710678118654752440f));
}
__device__ __forceinline__ void async16(const void* g, void* l) {
    __builtin_amdgcn_global_load_lds((const __attribute__((address_space(1))) void*)g,
                                     (__attribute__((address_space(3))) void*)l, 16, 0, 0);
}
__device__ __forceinline__ float med3f(float a, float b, float c) {
    float r;
    asm("v_med3_f32 %0, %1, %2, %3" : "=v"(r) : "v"(a), "v"(b), "v"(c));
    return r;
}

// ---------- ws layout (bytes) ----------
#define OFF_TE1   0u          // 8*384*4 = 12288
#define OFF_TE2   16384u      // 8*256*4 = 8192
#define OFF_BN1   28672u      // scale1(1024) shift1(1024)
#define OFF_BN2   30720u
#define OFF_WC1   1605632u    // 98304*2
#define OFF_WC2   1802240u    // 65536*2
#define OFF_P2T   2097152u    // 8*2048*256*2 = 8388608 (bf16)
#define OFF_X1    10485760u   // 8*8192*384*2 = 50331648 (bf16; Z reuses)
#define OFF_Y     60817408u   // 8*8192*256*2 = 33554432 (bf16)
// transient tenants:
#define OFF_PD    OFF_Y                     // knn dist partials (dead before gemm1 writes Y)
#define OFF_PI    (OFF_Y + 6291456u)        // 8*8*8192*3*4 = 6.29 MB each
#define OFF_PS    OFF_P2T                   // gemm stat partials [256ch][1024row] = 1 MB
#define OFF_PQ    (OFF_P2T + 1048576u)      // 1 MB (p2t dead by gemm time)

// ===================================================================
// mega1: knn partials (blocks 0..1023) + prep (1024..1415)
//        + transpose_p2 (1416..5511)
// ===================================================================
__global__ __launch_bounds__(256) void mega1_kernel(
    const float* __restrict__ xyz1, const float* __restrict__ xyz2,
    float* __restrict__ pd, int* __restrict__ pi,
    const float* __restrict__ w1, const float* __restrict__ w2,
    unsigned short* __restrict__ o1, unsigned short* __restrict__ o2,
    const float* __restrict__ t_embed,
    const float* __restrict__ w_t1, const float* __restrict__ b_t1,
    const float* __restrict__ w_t2, const float* __restrict__ b_t2,
    float* __restrict__ te1, float* __restrict__ te2,
    const float* __restrict__ p2, unsigned short* __restrict__ p2t)
{
    __shared__ __align__(16) char smem[4096];
    int bx = blockIdx.x, tid = threadIdx.x;

    if (bx < 1024) {
        // ---- knn partials ----
        float4* sp = (float4*)smem;
        int x = bx & 15, ch = (bx >> 4) & 7, b = bx >> 7;
        int s0 = ch * KCS;
        {
            int gs = s0 + tid;
            float xx = xyz2[(b * S_ + gs) * 3 + 0];
            float yy = xyz2[(b * S_ + gs) * 3 + 1];
            float zz = xyz2[(b * S_ + gs) * 3 + 2];
            sp[tid] = make_float4(xx, yy, zz, xx * xx + yy * yy + zz * zz);
        }
        __syncthreads();

        float nx[2], ny[2], nz[2], nn[2];
        float d1[2], d2[2], d3[2];
        int   i1[2], i2[2], i3[2];
        #pragma unroll
        for (int qq = 0; qq < 2; ++qq) {
            int n = x * KQB + qq * 256 + tid;
            float x1 = xyz1[(b * N_ + n) * 3 + 0];
            float y1 = xyz1[(b * N_ + n) * 3 + 1];
            float z1 = xyz1[(b * N_ + n) * 3 + 2];
            nn[qq] = x1 * x1 + y1 * y1 + z1 * z1;
            nx[qq] = -2.0f * x1; ny[qq] = -2.0f * y1; nz[qq] = -2.0f * z1;
            d1[qq] = FLT_MAX; d2[qq] = FLT_MAX; d3[qq] = FLT_MAX;
            i1[qq] = 0; i2[qq] = 0; i3[qq] = 0;
        }

        for (int s = 0; s < KCS; s += 4) {
            #pragma unroll
            for (int u = 0; u < 4; ++u) {
                float4 p = sp[s + u];
                int gi = s0 + s + u;
                #pragma unroll
                for (int qq = 0; qq < 2; ++qq) {
                    float d = fmaf(nx[qq], p.x,
                              fmaf(ny[qq], p.y,
                              fmaf(nz[qq], p.z, p.w)));
                    bool c1 = d < d1[qq];
                    bool c2 = d < d2[qq];
                    bool c3 = d < d3[qq];
                    float e1 = fminf(d1[qq], d);
                    float e2 = med3f(d1[qq], d2[qq], d);
                    float e3 = med3f(d2[qq], d3[qq], d);
                    int u1  = c1 ? i1[qq] : gi;
                    int n1i = c1 ? gi : i1[qq];
                    int n2i = c2 ? u1 : i2[qq];
                    int u2  = c2 ? i2[qq] : gi;
                    int n3i = c3 ? u2 : i3[qq];
                    d1[qq] = e1; d2[qq] = e2; d3[qq] = e3;
                    i1[qq] = n1i; i2[qq] = n2i; i3[qq] = n3i;
                }
            }
        }

        #pragma unroll
        for (int qq = 0; qq < 2; ++qq) {
            int n = x * KQB + qq * 256 + tid;
            size_t pb = (((size_t)b * KCH + ch) * N_ + n) * 3;
            pd[pb + 0] = d1[qq] + nn[qq];
            pd[pb + 1] = d2[qq] + nn[qq];
            pd[pb + 2] = d3[qq] + nn[qq];
            pi[pb + 0] = i1[qq]; pi[pb + 1] = i2[qq]; pi[pb + 2] = i3[qq];
        }
    } else if (bx < 1416) {
        // ---- prep: weight cvt + te1/te2 ----
        int pbx = bx - 1024;
        if (pbx < 384) {
            int g = pbx * 256 + tid;
            o1[g] = f2bf(w1[g]);
            if (g < CO_ * CO_) o2[g] = f2bf(w2[g]);
            return;
        }
        float* gt = (float*)smem;
        int b = pbx - 384;
        gt[tid] = gelu_f(t_embed[b * T_ + tid]);
        __syncthreads();
        for (int o = tid; o < CIN_ + CO_; o += 256) {
            if (o < CIN_) {
                const float* w = w_t1 + o * T_;
                float s = 0.f;
                for (int k = 0; k < T_; ++k) s += gt[k] * w[k];
                te1[b * CIN_ + o] = s + b_t1[o];
            } else {
                int oo = o - CIN_;
                const float* w = w_t2 + oo * T_;
                float s = 0.f;
                for (int k = 0; k < T_; ++k) s += gt[k] * w[k];
                te2[b * CO_ + oo] = s + b_t2[oo];
            }
        }
    } else {
        // ---- transpose p2 (B,C2,S) fp32 -> (B,S,C2) bf16 ----
        unsigned short (*tile)[33] = (unsigned short (*)[33])smem;
        int bz = bx - 1416;
        int b = bz >> 9, cy = (bz >> 6) & 7, sx = bz & 63;
        int s0 = sx * 32, c0 = cy * 32;
        int tx = tid & 31, ty = tid >> 5;
        #pragma unroll
        for (int j = 0; j < 4; ++j) {
            int c = ty + j * 8;
            tile[c][tx] = f2bf(p2[((size_t)b * C2_ + c0 + c) * S_ + s0 + tx]);
        }
        __syncthreads();
        #pragma unroll
        for (int j = 0; j < 4; ++j) {
            int s = ty + j * 8;
            p2t[((size_t)b * S_ + s0 + s) * C2_ + c0 + tx] = tile[tx][s];
        }
    }
}

// ===================================================================
// mega2: interp (blocks 0..8191) + transpose_p1 (8192..16383)
// ===================================================================
__global__ __launch_bounds__(256) void mega2_kernel(
    const float* __restrict__ pd, const int* __restrict__ pi,
    const unsigned short* __restrict__ p2t,
    const float* __restrict__ te1,
    const float* __restrict__ p1,
    unsigned short* __restrict__ X1)
{
    __shared__ __align__(16) char smem[4096];
    int bx = blockIdx.x, tid = threadIdx.x;

    if (bx < 8192) {
        // ---- merge partials + interp -> X1[:,128:384] ----
        float (*spd)[8][3] = (float (*)[8][3])smem;              // 768
        int   (*spi)[8][3] = (int (*)[8][3])(smem + 768);        // 768
        float* ste = (float*)(smem + 1536);                      // 1024
        int b = bx >> 10;
        int n0 = (bx & 1023) * 8;
        ste[tid] = te1[b * CIN_ + C1_ + tid];
        if (tid < 64) {
            int ch = tid >> 3, r = tid & 7;
            size_t pb = (((size_t)b * KCH + ch) * N_ + n0 + r) * 3;
            spd[ch][r][0] = pd[pb]; spd[ch][r][1] = pd[pb + 1]; spd[ch][r][2] = pd[pb + 2];
        } else if (tid < 128) {
            int t2 = tid - 64;
            int ch = t2 >> 3, r = t2 & 7;
            size_t pb = (((size_t)b * KCH + ch) * N_ + n0 + r) * 3;
            spi[ch][r][0] = pi[pb]; spi[ch][r][1] = pi[pb + 1]; spi[ch][r][2] = pi[pb + 2];
        }
        __syncthreads();

        int r = tid >> 5;
        int l = tid & 31;
        float d1, d2, d3; int i1, i2, i3;
        if (l < KCH) {
            d1 = spd[l][r][0]; d2 = spd[l][r][1]; d3 = spd[l][r][2];
            i1 = spi[l][r][0]; i2 = spi[l][r][1]; i3 = spi[l][r][2];
        } else {
            d1 = d2 = d3 = FLT_MAX;
            i1 = i2 = i3 = 0x7FFFFFFF;
        }
        #pragma unroll
        for (int m = 1; m <= 4; m <<= 1) {
            float pd1 = __shfl_xor(d1, m), pd2 = __shfl_xor(d2, m), pd3 = __shfl_xor(d3, m);
            int   pi1 = __shfl_xor(i1, m), pi2 = __shfl_xor(i2, m), pi3 = __shfl_xor(i3, m);
            #pragma unroll
            for (int k = 0; k < 3; ++k) {
                float d = (k == 0) ? pd1 : (k == 1) ? pd2 : pd3;
                int   i = (k == 0) ? pi1 : (k == 1) ? pi2 : pi3;
                bool c1 = (d < d1) || (d == d1 && i < i1);
                bool c2 = (d < d2) || (d == d2 && i < i2);
                bool c3 = (d < d3) || (d == d3 && i < i3);
                float e1 = c1 ? d : d1;        int j1 = c1 ? i : i1;
                float e2 = c1 ? d1 : (c2 ? d : d2);
                int   j2 = c1 ? i1 : (c2 ? i : i2);
                float e3 = c2 ? d2 : (c3 ? d : d3);
                int   j3 = c2 ? i2 : (c3 ? i : i3);
                d1 = e1; d2 = e2; d3 = e3; i1 = j1; i2 = j2; i3 = j3;
            }
        }
        int base = tid & 32;
        d1 = __shfl(d1, base); d2 = __shfl(d2, base); d3 = __shfl(d3, base);
        i1 = __shfl(i1, base); i2 = __shfl(i2, base); i3 = __shfl(i3, base);
        float r1 = 1.0f / (d1 + 1e-8f);
        float r2 = 1.0f / (d2 + 1e-8f);
        float r3 = 1.0f / (d3 + 1e-8f);
        float rs = 1.0f / (r1 + r2 + r3);
        float w0 = r1 * rs, w1 = r2 * rs, w2 = r3 * rs;

        int gr = (b << 13) + n0 + r;
        int co = l * 8;
        const unsigned short* q0 = p2t + ((size_t)b * S_ + i1) * C2_ + co;
        const unsigned short* q1 = p2t + ((size_t)b * S_ + i2) * C2_ + co;
        const unsigned short* q2 = p2t + ((size_t)b * S_ + i3) * C2_ + co;
        union { short8 v; unsigned short u[8]; } a0, a1, a2, pk;
        a0.v = *(const short8*)q0;
        a1.v = *(const short8*)q1;
        a2.v = *(const short8*)q2;
        #pragma unroll
        for (int jj = 0; jj < 8; ++jj) {
            float v = w0 * bf2f(a0.u[jj]) + w1 * bf2f(a1.u[jj]) + w2 * bf2f(a2.u[jj])
                    + ste[co + jj];
            pk.u[jj] = f2bf(v);
        }
        *(short8*)&X1[(size_t)gr * CIN_ + C1_ + co] = pk.v;
    } else {
        // ---- transpose p1 (B,128,N) fp32 + te1 -> X1[:,0:128] bf16 ----
        unsigned short (*tile)[33] = (unsigned short (*)[33])smem;
        int bz = bx - 8192;
        int b = bz >> 10, cy = (bz >> 8) & 3, nx = bz & 255;
        int n0 = nx * 32, c0 = cy * 32;
        int tx = tid & 31, ty = tid >> 5;
        const float* te = te1 + b * CIN_;
        #pragma unroll
        for (int j = 0; j < 4; ++j) {
            int c = ty + j * 8;
            tile[c][tx] =
                f2bf(p1[((size_t)b * C1_ + c0 + c) * N_ + n0 + tx] + te[c0 + c]);
        }
        __syncthreads();
        #pragma unroll
        for (int j = 0; j < 4; ++j) {
            int n = ty + j * 8;
            X1[((size_t)b * N_ + n0 + n) * CIN_ + c0 + tx] = tile[tx][n];
        }
    }
}

// ---------- GEMM (m97-style, B^T input) + partial-store BN stats ----------
template <int K, int MODE>
__global__ __launch_bounds__(256) void gemm_bt(
    const unsigned short* __restrict__ A,
    const unsigned short* __restrict__ X,
    const float* __restrict__ bias,
    unsigned short* __restrict__ out,
    float* __restrict__ psum, float* __restrict__ psq)
{
    __shared__ unsigned short sA[128 * 64];
    __shared__ unsigned short sB[128 * 64];
    const int tid = threadIdx.x;
    const int lane = tid & 63, wave = tid >> 6;
    const int wo = wave >> 1, wm = wave & 1;
    const int quad = lane >> 4, col = lane & 15;
    const int b = blockIdx.z;
    const int x = blockIdx.x;
    const int perm = (x & 7) * 16 + (x >> 3);
    const int n_t = perm >> 1, o_t = perm & 1;
    const int o0 = o_t * 128;
    const int n0 = n_t * 128;
    const unsigned short* Xb = X + (size_t)b * N_ * K;
    const int prow = ((b << 6) + n_t) * 2 + wm;

    f32x4 acc[4][4];
    #pragma unroll
    for (int i = 0; i < 4; ++i)
        #pragma unroll
        for (int j = 0; j < 4; ++j) acc[i][j] = (f32x4){0.f, 0.f, 0.f, 0.f};

    for (int k0 = 0; k0 < K; k0 += 64) {
        #pragma unroll
        for (int i = 0; i < 4; ++i) {
            int chunk = i * 256 + tid;
            int row = chunk >> 3, c8 = chunk & 7;
            async16(&A [(o0 + row) * K + k0 + c8 * 8], &sA[chunk * 8]);
            async16(&Xb[(size_t)(n0 + row) * K + k0 + c8 * 8], &sB[chunk * 8]);
        }
        __syncthreads();
        #pragma unroll
        for (int kk = 0; kk < 64; kk += 32) {
            short8 af[4], bfr[4];
            #pragma unroll
            for (int i = 0; i < 4; ++i)
                af[i] = *(const short8*)&sA[(wo * 64 + i * 16 + col) * 64 + kk + quad * 8];
            #pragma unroll
            for (int j = 0; j < 4; ++j)
                bfr[j] = *(const short8*)&sB[(wm * 64 + j * 16 + col) * 64 + kk + quad * 8];
            #pragma unroll
            for (int i = 0; i < 4; ++i)
                #pragma unroll
                for (int j = 0; j < 4; ++j)
                    acc[i][j] = __builtin_amdgcn_mfma_f32_16x16x32_bf16(af[i], bfr[j], acc[i][j], 0, 0, 0);
        }
        __syncthreads();
    }

    #pragma unroll
    for (int i = 0; i < 4; ++i) {
        int oo = o0 + wo * 64 + i * 16 + quad * 4;
        float bv0 = bias[oo + 0], bv1 = bias[oo + 1];
        float bv2 = bias[oo + 2], bv3 = bias[oo + 3];
        float s0 = 0.f, s1 = 0.f, s2 = 0.f, s3 = 0.f;
        float q0 = 0.f, q1 = 0.f, q2 = 0.f, q3 = 0.f;
        #pragma unroll
        for (int j = 0; j < 4; ++j) {
            int nn = n0 + wm * 64 + j * 16 + col;
            float v0 = acc[i][j][0] + bv0, v1 = acc[i][j][1] + bv1;
            float v2 = acc[i][j][2] + bv2, v3 = acc[i][j][3] + bv3;
            s0 += v0; q0 += v0 * v0; s1 += v1; q1 += v1 * v1;
            s2 += v2; q2 += v2 * v2; s3 += v3; q3 += v3 * v3;
            if (MODE == 0) {
                union { unsigned short u[4]; uint2 p; } pk;
                pk.u[0] = f2bf(v0); pk.u[1] = f2bf(v1);
                pk.u[2] = f2bf(v2); pk.u[3] = f2bf(v3);
                *(uint2*)&out[((size_t)b * N_ + nn) * CO_ + oo] = pk.p;
            } else {
                out[((size_t)b * CO_ + oo + 0) * N_ + nn] = f2bf(v0);
                out[((size_t)b * CO_ + oo + 1) * N_ + nn] = f2bf(v1);
                out[((size_t)b * CO_ + oo + 2) * N_ + nn] = f2bf(v2);
                out[((size_t)b * CO_ + oo + 3) * N_ + nn] = f2bf(v3);
            }
        }
        #pragma unroll
        for (int off = 1; off < 16; off <<= 1) {
            s0 += __shfl_down(s0, off); q0 += __shfl_down(q0, off);
            s1 += __shfl_down(s1, off); q1 += __shfl_down(q1, off);
            s2 += __shfl_down(s2, off); q2 += __shfl_down(q2, off);
            s3 += __shfl_down(s3, off); q3 += __shfl_down(q3, off);
        }
        if (col == 0) {
            float* ps = psum + (size_t)oo * 1024 + prow;
            float* pq = psq  + (size_t)oo * 1024 + prow;
            ps[0] = s0; ps[1024] = s1; ps[2048] = s2; ps[3072] = s3;
            pq[0] = q0; pq[1024] = q1; pq[2048] = q2; pq[3072] = q3;
        }
    }
}

// ---------- reduce partials (ch-major, coalesced) + BN scale/shift ----------
__global__ __launch_bounds__(256) void bn_reduce_kernel(
    const float* __restrict__ psum, const float* __restrict__ psq,
    const float* __restrict__ gamma, const float* __restrict__ beta,
    float* __restrict__ scale, float* __restrict__ shift)
{
    int ch = blockIdx.x * 8 + (threadIdx.x >> 5);   // grid 32
    int l = threadIdx.x & 31;
    float s = 0.f, q = 0.f;
    for (int r = l; r < 1024; r += 32) {
        s += psum[(size_t)ch * 1024 + r];
        q += psq [(size_t)ch * 1024 + r];
    }
    #pragma unroll
    for (int off = 16; off > 0; off >>= 1) {
        s += __shfl_down(s, off, 32);
        q += __shfl_down(q, off, 32);
    }
    if (l == 0) {
        const float inv = 1.0f / 65536.0f;
        float m = s * inv;
        float var = fmaxf(q * inv - m * m, 0.f);
        float sc = gamma[ch] / sqrtf(var + 1e-5f);
        scale[ch] = sc;
        shift[ch] = beta[ch] - m * sc;
    }
}

// ---------- in-place: x2 = gelu(scale*y + shift) + te2, layout (B,N,256) bf16 ----------
__global__ __launch_bounds__(256) void apply1_kernel(
    unsigned short* __restrict__ y, const float* __restrict__ scale,
    const float* __restrict__ shift, const float* __restrict__ te2)
{
    __shared__ float ssc[CO_], ssh[CO_], ste[CO_];
    int b = blockIdx.x >> 10;
    int t = threadIdx.x;
    ssc[t] = scale[t]; ssh[t] = shift[t]; ste[t] = te2[b * CO_ + t];
    __syncthreads();
    int g = blockIdx.x * 256 + t;
    int row = g >> 5;
    int og = (g & 31) * 8;
    unsigned short* p = y + (size_t)row * CO_ + og;
    union { short8 v; unsigned short u[8]; } in, op;
    in.v = *(short8*)p;
    #pragma unroll
    for (int jj = 0; jj < 8; ++jj) {
        int o = og + jj;
        op.u[jj] = f2bf(gelu_f(ssc[o] * bf2f(in.u[jj]) + ssh[o]) + ste[o]);
    }
    *(short8*)p = op.v;
}

// ---------- final: out = gelu(scale*z + shift), layout (B,256,N), fp32 out ----------
__global__ __launch_bounds__(256) void final_kernel(
    const unsigned short* __restrict__ z, const float* __restrict__ scale,
    const float* __restrict__ shift, float* __restrict__ out)
{
    int g = blockIdx.x * 256 + threadIdx.x;
    size_t e = (size_t)g * 8;
    int row = (int)(e >> 13);
    int o = row & (CO_ - 1);
    float sc = scale[o], sh = shift[o];
    union { short8 v; unsigned short u[8]; } in;
    in.v = *(const short8*)&z[e];
    float vo[8];
    #pragma unroll
    for (int jj = 0; jj < 8; ++jj)
        vo[jj] = gelu_f(sc * bf2f(in.u[jj]) + sh);
    *(float4*)&out[e]     = make_float4(vo[0], vo[1], vo[2], vo[3]);
    *(float4*)&out[e + 4] = make_float4(vo[4], vo[5], vo[6], vo[7]);
}

// ---------- launch ----------
extern "C" void kernel_launch(void* const* d_in, const int* in_sizes, int n_in,
                              void* d_out, int out_size, void* d_ws, size_t ws_size,
                              hipStream_t stream)
{
    (void)in_sizes; (void)n_in; (void)out_size; (void)ws_size;
    const float* xyz1    = (const float*)d_in[0];
    const float* xyz2    = (const float*)d_in[1];
    const float* points1 = (const float*)d_in[2];
    const float* points2 = (const float*)d_in[3];
    const float* t_embed = (const float*)d_in[4];
    const float* w_t1    = (const float*)d_in[5];
    const float* b_t1    = (const float*)d_in[6];
    const float* w_c1    = (const float*)d_in[7];
    const float* b_c1    = (const float*)d_in[8];
    const float* g1      = (const float*)d_in[9];
    const float* be1     = (const float*)d_in[10];
    const float* w_t2    = (const float*)d_in[11];
    const float* b_t2    = (const float*)d_in[12];
    const float* w_c2    = (const float*)d_in[13];
    const float* b_c2    = (const float*)d_in[14];
    const float* g2      = (const float*)d_in[15];
    const float* be2     = (const float*)d_in[16];

    char* w = (char*)d_ws;
    float* te1        = (float*)(w + OFF_TE1);
    float* te2        = (float*)(w + OFF_TE2);
    float* scale1     = (float*)(w + OFF_BN1);
    float* shift1     = scale1 + 256;
    float* scale2     = (float*)(w + OFF_BN2);
    float* shift2     = scale2 + 256;
    unsigned short* wc1 = (unsigned short*)(w + OFF_WC1);
    unsigned short* wc2 = (unsigned short*)(w + OFF_WC2);
    unsigned short* p2t = (unsigned short*)(w + OFF_P2T);
    float* pd         = (float*)(w + OFF_PD);
    int*   pi         = (int*)(w + OFF_PI);
    float* psum       = (float*)(w + OFF_PS);
    float* psq        = (float*)(w + OFF_PQ);
    unsigned short* X1  = (unsigned short*)(w + OFF_X1);
    unsigned short* Z   = (unsigned short*)(w + OFF_X1);
    unsigned short* Y   = (unsigned short*)(w + OFF_Y);
    float* out = (float*)d_out;

    hipLaunchKernelGGL(mega1_kernel, dim3(5512), dim3(256), 0, stream,
                       xyz1, xyz2, pd, pi,
                       w_c1, w_c2, wc1, wc2,
                       t_embed, w_t1, b_t1, w_t2, b_t2, te1, te2,
                       points2, p2t);
    hipLaunchKernelGGL(mega2_kernel, dim3(16384), dim3(256), 0, stream,
                       pd, pi, p2t, te1, points1, X1);
    // gemm1 writes Y, overwriting pd/pi (dead after mega2); psum/psq overwrite p2t (dead)
    hipLaunchKernelGGL((gemm_bt<CIN_, 0>), dim3(128, 1, B_), dim3(256), 0, stream,
                       wc1, X1, b_c1, Y, psum, psq);
    hipLaunchKernelGGL(bn_reduce_kernel, dim3(32), dim3(256), 0, stream,
                       psum, psq, g1, be1, scale1, shift1);
    hipLaunchKernelGGL(apply1_kernel, dim3(8192), dim3(256), 0, stream,
                       Y, scale1, shift1, te2);
    hipLaunchKernelGGL((gemm_bt<CO_, 1>), dim3(128, 1, B_), dim3(256), 0, stream,
                       wc2, Y, b_c2, Z, psum, psq);
    hipLaunchKernelGGL(bn_reduce_kernel, dim3(32), dim3(256), 0, stream,
                       psum, psq, g2, be2, scale2, shift2);
    hipLaunchKernelGGL(final_kernel, dim3(8192), dim3(256), 0, stream,
                       Z, scale2, shift2, out);
}